// Round 8
// baseline (330.080 us; speedup 1.0000x reference)
//
#include <hip/hip_runtime.h>
#include <hip/hip_bf16.h>
#include <math.h>

#define D_MODEL 768
#define D_STATE 64
#define D_CONV 4
#define D_INNER 1536
#define HEADDIM 64
#define NHEADS 24
#define RANK 8
#define D_IN_PROJ 3224   // 2*1536 + 2*64 + 24
#define NPAD 3328        // D_IN_PROJ padded to multiple of 128
#define ZSTR 3328        // zx row stride (padded)
#define CONV_DIM 1664    // 1536 + 128
#define BSZ 2
#define SEQ 1024
#define NROWS (BSZ*SEQ)  // 2048
#define SCALE_LORA 2.0f  // 16/8
#define LC 64            // chunk length
#define NCHUNK (SEQ/LC)  // 16
#define LSTR 72          // LDS row stride (bf16): 144B -> 2-way banks on 16-row column reads

typedef __attribute__((ext_vector_type(8))) short bf16x8;
typedef __attribute__((ext_vector_type(4))) float f32x4;

// ---------------- helpers ----------------

__device__ inline float waveReduceSum(float v) {
#pragma unroll
    for (int m = 32; m; m >>= 1) v += __shfl_xor(v, m, 64);
    return v;
}

template <int NWAVES>
__device__ inline float blockReduceSum(float v) {
    __shared__ float tmp[NWAVES];
    int lane = threadIdx.x & 63, wid = threadIdx.x >> 6;
    v = waveReduceSum(v);
    if (lane == 0) tmp[wid] = v;
    __syncthreads();
    float tot = 0.f;
#pragma unroll
    for (int i = 0; i < NWAVES; i++) tot += tmp[i];
    return tot;
}

__device__ inline float sigmoidf_(float x) { return 1.f / (1.f + expf(-x)); }

// float -> bf16 (round-to-nearest-even)
__device__ inline unsigned short f2bf(float f) {
    union { float f; unsigned int u; } v; v.f = f;
    unsigned int r = (v.u + 0x7fffu + ((v.u >> 16) & 1u)) >> 16;
    return (unsigned short)r;
}
__device__ inline float bf2f(unsigned short u) {
    union { unsigned int i; float f; } v; v.i = ((unsigned int)u) << 16; return v.f;
}

__device__ inline void load_lds16(const void* g, void* l) {
    __builtin_amdgcn_global_load_lds((const __attribute__((address_space(1))) void*)g,
                                     (__attribute__((address_space(3))) void*)l, 16, 0, 0);
}

// ---------------- weight build (f32 base + LoRA -> bf16) ----------------

__global__ void build_w_in_kernel(const float* __restrict__ base,
                                  const float* __restrict__ lA,
                                  const float* __restrict__ lB,
                                  unsigned short* __restrict__ W) {  // [NPAD][D_MODEL]
    int idx = blockIdx.x * blockDim.x + threadIdx.x;
    if (idx >= NPAD * D_MODEL) return;
    int r = idx / D_MODEL, c = idx - r * D_MODEL;
    if (r >= D_IN_PROJ) { W[idx] = 0; return; }
    float s = 0.f;
#pragma unroll
    for (int k = 0; k < RANK; k++) s += lB[r * RANK + k] * lA[k * D_MODEL + c];
    W[idx] = f2bf(base[(size_t)r * D_MODEL + c] + SCALE_LORA * s);
}

__global__ void build_w_out_kernel(const float* __restrict__ base,
                                   const float* __restrict__ lA,
                                   const float* __restrict__ lB,
                                   unsigned short* __restrict__ W) { // [D_MODEL][D_INNER]
    int idx = blockIdx.x * blockDim.x + threadIdx.x;
    if (idx >= D_MODEL * D_INNER) return;
    int r = idx / D_INNER, c = idx - r * D_INNER;
    float s = 0.f;
#pragma unroll
    for (int k = 0; k < RANK; k++) s += lB[r * RANK + k] * lA[k * D_INNER + c];
    W[idx] = f2bf(base[idx] + SCALE_LORA * s);
}

// ---------------- rmsnorm + rope -> bf16 ----------------
__global__ __launch_bounds__(384) void rmsrope_kernel(
    const float* __restrict__ x, const float* __restrict__ w,
    unsigned short* __restrict__ out, int loop_i) {
    int row = blockIdx.x;
    const float* xr = x + (size_t)row * D_MODEL;
    int j = threadIdx.x;
    float x0 = xr[2 * j], x1 = xr[2 * j + 1];
    float ss = blockReduceSum<6>(x0 * x0 + x1 * x1);
    float sc = rsqrtf(ss * (1.f / D_MODEL) + 1e-6f);
    float y0 = x0 * sc * w[2 * j];
    float y1 = x1 * sc * w[2 * j + 1];
    float ang = (float)loop_i * expf((float)(2 * j) * (-9.210340371976184f / (float)D_MODEL));
    float c = cosf(ang), sn = sinf(ang);
    unsigned short* orow = out + (size_t)row * D_MODEL;
    orow[2 * j]     = f2bf(y0 * c - y1 * sn);
    orow[2 * j + 1] = f2bf(y1 * c + y0 * sn);
}

// ---------------- bf16 MFMA GEMM, 2-phase prefetch dbuf + swizzled LDS ----------------
// MODE 1: f32 atomicAdd (split-K GEMM2). MODE 2: bf16 store + f32 dt side-channel (GEMM1).
template <int MODE>
__global__ __launch_bounds__(256) void gemm_pipe_kernel(
    const unsigned short* __restrict__ A,
    const unsigned short* __restrict__ B,
    void* __restrict__ Cv, int M, int N, int K, int Cstride,
    int Ks, float* __restrict__ dtraw) {
    __shared__ unsigned short lsA[2][128 * 64];
    __shared__ unsigned short lsB[2][128 * 64];
    int t = threadIdx.x;
    int w = t >> 6, lane = t & 63;
    int n0 = blockIdx.x * 128, m0 = blockIdx.y * 128;
    int kbase = blockIdx.z * Ks;
    int wr = w >> 1, wc = w & 1;
    f32x4 acc[4][4];
#pragma unroll
    for (int i = 0; i < 4; i++)
#pragma unroll
        for (int j = 0; j < 4; j++) acc[i][j] = (f32x4){0.f, 0.f, 0.f, 0.f};

#define STAGE(bi, kk0)                                                           \
    {                                                                            \
        _Pragma("unroll")                                                        \
        for (int o = 0; o < 4; o++) {                                            \
            int s = o * 256 + t;                                                 \
            int row = s >> 3, u = s & 7;                                         \
            int usrc = (u ^ (row & 7)) << 3;                                     \
            unsigned short* la = &lsA[bi][(size_t)(o * 256 + (t & ~63)) * 8];    \
            unsigned short* lb = &lsB[bi][(size_t)(o * 256 + (t & ~63)) * 8];    \
            load_lds16(&A[(size_t)(m0 + row) * K + (kk0) + usrc], la);           \
            load_lds16(&B[(size_t)(n0 + row) * K + (kk0) + usrc], lb);           \
        }                                                                        \
    }

    int nk = Ks >> 6;
    STAGE(0, kbase);
    __syncthreads();           // drains vmcnt(0): buffer 0 ready
    int cur = 0;
    for (int ks = 0; ks < nk; ks++) {
        if (ks + 1 < nk) STAGE(cur ^ 1, kbase + (ks + 1) * 64);   // prefetch next
#pragma unroll
        for (int kk = 0; kk < 2; kk++) {
            bf16x8 af[4], bfr[4];
            int u_t = kk * 4 + (lane >> 4);
            int kof = (u_t ^ (lane & 7)) << 3;    // swizzled read column
#pragma unroll
            for (int i = 0; i < 4; i++) {
                int row = wr * 64 + i * 16 + (lane & 15);
                af[i] = *(const bf16x8*)&lsA[cur][row * 64 + kof];
            }
#pragma unroll
            for (int j = 0; j < 4; j++) {
                int row = wc * 64 + j * 16 + (lane & 15);
                bfr[j] = *(const bf16x8*)&lsB[cur][row * 64 + kof];
            }
#pragma unroll
            for (int i = 0; i < 4; i++)
#pragma unroll
                for (int j = 0; j < 4; j++)
                    acc[i][j] = __builtin_amdgcn_mfma_f32_16x16x32_bf16(af[i], bfr[j], acc[i][j], 0, 0, 0);
        }
        __syncthreads();       // all waves done with cur; prefetch (vmcnt 0) landed
        cur ^= 1;
    }
#undef STAGE

#pragma unroll
    for (int i = 0; i < 4; i++) {
#pragma unroll
        for (int j = 0; j < 4; j++) {
#pragma unroll
            for (int r = 0; r < 4; r++) {
                int row = m0 + wr * 64 + i * 16 + (lane >> 4) * 4 + r;
                int col = n0 + wc * 64 + j * 16 + (lane & 15);
                float v = acc[i][j][r];
                if (MODE == 1) {
                    atomicAdd(&((float*)Cv)[(size_t)row * Cstride + col], v);
                } else {
                    ((unsigned short*)Cv)[(size_t)row * Cstride + col] = f2bf(v);
                    if (col >= 3200 && col < 3224) dtraw[row * 24 + (col - 3200)] = v;
                }
            }
        }
    }
}

// ---------------- depthwise causal conv + silu (B/C channels only) ----------------
// xbc layout: [NROWS][128]  (0..63 = B, 64..127 = C)
__global__ void conv_bc_kernel(const unsigned short* __restrict__ zxb,
                               const float* __restrict__ cw,
                               const float* __restrict__ cb, float* __restrict__ xbc) {
    int idx = blockIdx.x * blockDim.x + threadIdx.x;   // NROWS*128
    if (idx >= NROWS * 128) return;
    int cbc = idx & 127;
    int row = idx >> 7;
    int l = row & (SEQ - 1);
    int ch = 1536 + cbc;                               // conv channel
    const unsigned short* base = zxb + (size_t)row * ZSTR + 3072 + cbc;
    float acc = cb[ch];
#pragma unroll
    for (int t = 0; t < 4; t++) {
        int ll = l - 3 + t;
        if (ll >= 0) acc = fmaf(cw[ch * 4 + t], bf2f(base[(size_t)(ll - l) * ZSTR]), acc);
    }
    xbc[idx] = acc * sigmoidf_(acc);
}

// ---------------- MFMA chunked scan (X-conv fused) ----------------
__global__ __launch_bounds__(256) void scan_mfma_kernel(
    const unsigned short* __restrict__ zxb,  // [NROWS][ZSTR] bf16
    const float* __restrict__ xbc,           // [NROWS][128]  (B|C)
    const float* __restrict__ dtraw,         // [NROWS][24] f32
    const float* __restrict__ cw, const float* __restrict__ cb,
    const float* __restrict__ dt_bias,
    const float* __restrict__ A_log,
    const float* __restrict__ Dp,
    float* __restrict__ y,           // [NROWS][D_INNER]
    float* __restrict__ Fbuf,        // [blk][n][p]
    float* __restrict__ cumA) {      // [blk][LC]
    __shared__ unsigned short Cc[64][LSTR];
    __shared__ unsigned short Bb[64][LSTR];
    __shared__ unsigned short Xt[64][LSTR];   // Xt[p][u]
    __shared__ unsigned short Bw[64][LSTR];   // Bw[n][u]
    __shared__ unsigned short Mm[64][LSTR];
    __shared__ float s_lds[64];
    __shared__ float dt_lds[64];

    int blk = blockIdx.x;
    int c = blk % NCHUNK;
    int bh = blk / NCHUNK;
    int h = bh % NHEADS, b = bh / NHEADS;
    int tid = threadIdx.x;
    int w = tid >> 6, lane = tid & 63;
    const int t0 = c * LC;

    if (w == 0) {
        int t = lane;
        size_t row = (size_t)(b * SEQ + t0 + t);
        float raw = dtraw[row * 24 + h] + dt_bias[h];
        float dt_t = raw > 20.f ? raw : log1pf(expf(raw));
        float s = dt_t * (-expf(A_log[h]));
#pragma unroll
        for (int off = 1; off < 64; off <<= 1) {
            float v = __shfl_up(s, off, 64);
            if (lane >= off) s += v;
        }
        s_lds[t] = s;
        dt_lds[t] = dt_t;
        cumA[(size_t)blk * LC + t] = expf(s);
    }

    float breg[16];
#pragma unroll
    for (int k = 0; k < 16; k++) {
        int idx = k * 256 + tid;
        int r = idx >> 6, ci = idx & 63;
        int l = t0 + r;
        size_t grow = (size_t)(b * SEQ + l);
        // fused X depthwise conv + silu
        int ch = h * 64 + ci;
        float accv = cb[ch];
        const unsigned short* xin = zxb + grow * ZSTR + 1536 + ch;
#pragma unroll
        for (int tap = 0; tap < 4; tap++) {
            int ll = l - 3 + tap;
            if (ll >= 0) accv = fmaf(cw[ch * 4 + tap], bf2f(xin[(size_t)(tap - 3) * ZSTR]), accv);
        }
        float xv = accv * sigmoidf_(accv);
        Xt[ci][r] = f2bf(xv);
        // B, C from small xbc
        float bv = xbc[grow * 128 + ci];
        float cv = xbc[grow * 128 + 64 + ci];
        Cc[r][ci] = f2bf(cv);
        Bb[r][ci] = f2bf(bv);
        breg[k] = bv;
    }
    __syncthreads();

    float s63 = s_lds[63];
#pragma unroll
    for (int k = 0; k < 16; k++) {
        int idx = k * 256 + tid;
        int r = idx >> 6, ci = idx & 63;
        float wu = expf(s63 - s_lds[r]) * dt_lds[r];
        Bw[ci][r] = f2bf(breg[k] * wu);
    }

    f32x4 accG[4];
#pragma unroll
    for (int j = 0; j < 4; j++) accG[j] = (f32x4){0.f, 0.f, 0.f, 0.f};
#pragma unroll
    for (int kk = 0; kk < 2; kk++) {
        int kof = kk * 32 + (lane >> 4) * 8;
        bf16x8 afr = *(const bf16x8*)&Cc[16 * w + (lane & 15)][kof];
#pragma unroll
        for (int j = 0; j < 4; j++) {
            bf16x8 bfr = *(const bf16x8*)&Bb[16 * j + (lane & 15)][kof];
            accG[j] = __builtin_amdgcn_mfma_f32_16x16x32_bf16(afr, bfr, accG[j], 0, 0, 0);
        }
    }
#pragma unroll
    for (int j = 0; j < 4; j++) {
#pragma unroll
        for (int r = 0; r < 4; r++) {
            int t = 16 * w + (lane >> 4) * 4 + r;
            int u = 16 * j + (lane & 15);
            float v = 0.f;
            if (u <= t) v = accG[j][r] * dt_lds[u] * expf(s_lds[t] - s_lds[u]);
            Mm[t][u] = f2bf(v);
        }
    }
    __syncthreads();

    f32x4 accY[4];
#pragma unroll
    for (int j = 0; j < 4; j++) accY[j] = (f32x4){0.f, 0.f, 0.f, 0.f};
#pragma unroll
    for (int kk = 0; kk < 2; kk++) {
        int kof = kk * 32 + (lane >> 4) * 8;
        bf16x8 afr = *(const bf16x8*)&Mm[16 * w + (lane & 15)][kof];
#pragma unroll
        for (int j = 0; j < 4; j++) {
            bf16x8 bfr = *(const bf16x8*)&Xt[16 * j + (lane & 15)][kof];
            accY[j] = __builtin_amdgcn_mfma_f32_16x16x32_bf16(afr, bfr, accY[j], 0, 0, 0);
        }
    }
    float D_h = Dp[h];
#pragma unroll
    for (int j = 0; j < 4; j++) {
#pragma unroll
        for (int r = 0; r < 4; r++) {
            int t = 16 * w + (lane >> 4) * 4 + r;
            int p = 16 * j + (lane & 15);
            size_t row = (size_t)(b * SEQ + t0 + t);
            float xv = bf2f(Xt[p][t]);
            y[row * D_INNER + h * HEADDIM + p] = accY[j][r] + D_h * xv;
        }
    }

    f32x4 accF[4];
#pragma unroll
    for (int j = 0; j < 4; j++) accF[j] = (f32x4){0.f, 0.f, 0.f, 0.f};
#pragma unroll
    for (int kk = 0; kk < 2; kk++) {
        int kof = kk * 32 + (lane >> 4) * 8;
        bf16x8 afr = *(const bf16x8*)&Bw[16 * w + (lane & 15)][kof];
#pragma unroll
        for (int j = 0; j < 4; j++) {
            bf16x8 bfr = *(const bf16x8*)&Xt[16 * j + (lane & 15)][kof];
            accF[j] = __builtin_amdgcn_mfma_f32_16x16x32_bf16(afr, bfr, accF[j], 0, 0, 0);
        }
    }
#pragma unroll
    for (int j = 0; j < 4; j++) {
#pragma unroll
        for (int r = 0; r < 4; r++) {
            int n = 16 * w + (lane >> 4) * 4 + r;
            int p = 16 * j + (lane & 15);
            Fbuf[(size_t)blk * (HEADDIM * D_STATE) + n * HEADDIM + p] = accF[j][r];
        }
    }
}

// ---------------- combine: parallel over (bh, np-group); chain over 16 chunks ----------------
__global__ __launch_bounds__(256) void combine_kernel(
    const float* __restrict__ Fbuf, const float* __restrict__ cumA,
    float* __restrict__ Hinit) {
    int bh = blockIdx.x >> 4;
    int np = (blockIdx.x & 15) * 256 + threadIdx.x;
    float H = 0.f;
#pragma unroll
    for (int c = 0; c < NCHUNK; c++) {
        size_t idx = (size_t)(bh * NCHUNK + c) * (HEADDIM * D_STATE) + np;
        float pA = cumA[(size_t)(bh * NCHUNK + c) * LC + (LC - 1)];
        Hinit[idx] = H;
        H = fmaf(pA, H, Fbuf[idx]);
    }
}

// ---------------- ycorr: y += cumA[t] * C_t . Hinit  (Hinit layout [n][p]) ----------------
__global__ __launch_bounds__(256) void ycorr_kernel(
    const float* __restrict__ xbc, const float* __restrict__ cumA,
    const float* __restrict__ Hinit, float* __restrict__ y) {
    int blk = blockIdx.x;
    int c = blk % NCHUNK;
    int bh = blk / NCHUNK;
    int h = bh % NHEADS, b = bh / NHEADS;
    __shared__ float Cd[LC][D_STATE + 1];
    __shared__ float Hs[D_STATE][HEADDIM + 1];
    int tid = threadIdx.x;
    size_t cbase = (size_t)blk * LC;
    size_t hbase = (size_t)blk * (HEADDIM * D_STATE);
#pragma unroll
    for (int k = 0; k < 16; k++) {
        int idx = tid + k * 256;
        int r = idx >> 6, n = idx & 63;
        size_t row = (size_t)(b * SEQ + c * LC + r);
        Cd[r][n] = xbc[row * 128 + 64 + n] * cumA[cbase + r];
        Hs[r][n] = Hinit[hbase + idx];
    }
    __syncthreads();
    int tx = tid & 15, ty = tid >> 4;
    float acc[4][4] = {};
    for (int n = 0; n < D_STATE; n++) {
        float cv[4], hv[4];
#pragma unroll
        for (int i = 0; i < 4; i++) cv[i] = Cd[ty * 4 + i][n];
#pragma unroll
        for (int j = 0; j < 4; j++) hv[j] = Hs[n][tx * 4 + j];
#pragma unroll
        for (int i = 0; i < 4; i++)
#pragma unroll
            for (int j = 0; j < 4; j++)
                acc[i][j] = fmaf(cv[i], hv[j], acc[i][j]);
    }
#pragma unroll
    for (int i = 0; i < 4; i++) {
        int tt = ty * 4 + i;
        size_t row = (size_t)(b * SEQ + c * LC + tt);
#pragma unroll
        for (int j = 0; j < 4; j++) {
            int p = tx * 4 + j;
            size_t oidx = row * D_INNER + h * HEADDIM + p;
            y[oidx] += acc[i][j];
        }
    }
}

// ---------------- gated rmsnorm -> bf16, + GEMM2 epilogue init ----------------
__global__ __launch_bounds__(256) void gatenorm_kernel(
    const float* __restrict__ y, const unsigned short* __restrict__ zxb,
    const float* __restrict__ w, unsigned short* __restrict__ out,
    const float* __restrict__ xp, const float* __restrict__ gate,
    float* __restrict__ outbuf) {
    int row = blockIdx.x;
    const unsigned short* z = zxb + (size_t)row * ZSTR;
    const float* yr = y + (size_t)row * D_INNER;
    float g[6];
    float ss = 0.f;
#pragma unroll
    for (int e = 0; e < 6; e++) {
        int idx = threadIdx.x + e * 256;
        float zv = bf2f(z[idx]);
        float gv = yr[idx] * (zv * sigmoidf_(zv));
        g[e] = gv;
        ss += gv * gv;
    }
    ss = blockReduceSum<4>(ss);
    float sc = rsqrtf(ss * (1.f / D_INNER) + 1e-6f);
#pragma unroll
    for (int e = 0; e < 6; e++) {
        int idx = threadIdx.x + e * 256;
        out[(size_t)row * D_INNER + idx] = f2bf(g[e] * sc * w[idx]);
    }
    // GEMM2 epilogue init for this row: outbuf = gate * xp
    if (threadIdx.x < 192) {
        int q = threadIdx.x;
        float4 xv4 = ((const float4*)(xp + (size_t)row * D_MODEL))[q];
        float4 g4 = ((const float4*)gate)[q];
        ((float4*)(outbuf + (size_t)row * D_MODEL))[q] =
            make_float4(g4.x * xv4.x, g4.y * xv4.y, g4.z * xv4.z, g4.w * xv4.w);
    }
}

// ---------------- launch ----------------
extern "C" void kernel_launch(void* const* d_in, const int* in_sizes, int n_in,
                              void* d_out, int out_size, void* d_ws, size_t ws_size,
                              hipStream_t stream) {
    const float* x        = (const float*)d_in[0];
    const float* x_prompt = (const float*)d_in[1];
    const float* in_base  = (const float*)d_in[2];
    const float* lA_in    = (const float*)d_in[3];
    const float* lB_in    = (const float*)d_in[4];
    const float* conv_w   = (const float*)d_in[5];
    const float* conv_b   = (const float*)d_in[6];
    const float* dt_bias  = (const float*)d_in[7];
    const float* A_log    = (const float*)d_in[8];
    const float* D_param  = (const float*)d_in[9];
    const float* gnw      = (const float*)d_in[10];
    const float* out_base = (const float*)d_in[11];
    const float* lA_out   = (const float*)d_in[12];
    const float* lB_out   = (const float*)d_in[13];
    const float* loop_nw  = (const float*)d_in[14];
    const float* gate     = (const float*)d_in[15];
    float* out = (float*)d_out;

    float* ws_f = (float*)d_ws;
    float* dtraw = ws_f;                                   // 2048*24 f32
    float* xbc   = dtraw + (size_t)NROWS * 24;             // 2048*128 f32
    float* ybuf  = xbc   + (size_t)NROWS * 128;            // 2048*1536 f32
    float* Fbuf  = ybuf  + (size_t)NROWS * D_INNER;        // 768*4096 f32
    float* Hinit = Fbuf  + (size_t)BSZ * NHEADS * NCHUNK * HEADDIM * D_STATE;
    float* cumA  = Hinit + (size_t)BSZ * NHEADS * NCHUNK * HEADDIM * D_STATE; // 768*64
    unsigned short* zxb   = (unsigned short*)(cumA + (size_t)BSZ * NHEADS * NCHUNK * LC); // 2048*3328 bf16
    unsigned short* W_in  = zxb   + (size_t)NROWS * ZSTR;
    unsigned short* W_out = W_in  + (size_t)NPAD * D_MODEL;
    unsigned short* hbuf  = W_out + (size_t)D_MODEL * D_INNER;
    unsigned short* ygt   = hbuf  + (size_t)NROWS * D_MODEL;

    build_w_in_kernel<<<(NPAD * D_MODEL + 255) / 256, 256, 0, stream>>>(in_base, lA_in, lB_in, W_in);
    build_w_out_kernel<<<(D_MODEL * D_INNER + 255) / 256, 256, 0, stream>>>(out_base, lA_out, lB_out, W_out);

    for (int i = 0; i < 2; i++) {   // n_loops = 2 (fixed by setup_inputs)
        const float* xsrc = (i == 0) ? x : out;
        rmsrope_kernel<<<NROWS, 384, 0, stream>>>(xsrc, loop_nw, hbuf, i);

        // GEMM1: zxb(bf16) = hbuf . W_in^T  (+ dt raw f32 side-channel)
        dim3 g1(NPAD / 128, NROWS / 128, 1);
        gemm_pipe_kernel<2><<<g1, 256, 0, stream>>>(hbuf, W_in, zxb, NROWS, NPAD, D_MODEL, ZSTR,
                                                    D_MODEL, dtraw);

        conv_bc_kernel<<<(NROWS * 128 + 255) / 256, 256, 0, stream>>>(zxb, conv_w, conv_b, xbc);

        scan_mfma_kernel<<<BSZ * NHEADS * NCHUNK, 256, 0, stream>>>(
            zxb, xbc, dtraw, conv_w, conv_b, dt_bias, A_log, D_param, ybuf, Fbuf, cumA);
        combine_kernel<<<BSZ * NHEADS * 16, 256, 0, stream>>>(Fbuf, cumA, Hinit);
        ycorr_kernel<<<BSZ * NHEADS * NCHUNK, 256, 0, stream>>>(xbc, cumA, Hinit, ybuf);

        gatenorm_kernel<<<NROWS, 256, 0, stream>>>(ybuf, zxb, gnw, ygt, x_prompt, gate, out);

        // GEMM2: out += ygt . W_out^T  (split-K=4, atomic; init done in gatenorm)
        dim3 g2(D_MODEL / 128, NROWS / 128, 4);
        gemm_pipe_kernel<1><<<g2, 256, 0, stream>>>(ygt, W_out, out, NROWS, D_MODEL, D_INNER, D_MODEL,
                                                    D_INNER / 4, nullptr);
    }
}

// Round 9
// 330.034 us; speedup vs baseline: 1.0001x; 1.0001x over previous
//
#include <hip/hip_runtime.h>
#include <hip/hip_bf16.h>
#include <math.h>

#define D_MODEL 768
#define D_STATE 64
#define D_CONV 4
#define D_INNER 1536
#define HEADDIM 64
#define NHEADS 24
#define RANK 8
#define D_IN_PROJ 3224   // 2*1536 + 2*64 + 24
#define NPAD 3328        // D_IN_PROJ padded to multiple of 128
#define ZSTR 3328        // zx row stride (padded)
#define CONV_DIM 1664    // 1536 + 128
#define BSZ 2
#define SEQ 1024
#define NROWS (BSZ*SEQ)  // 2048
#define SCALE_LORA 2.0f  // 16/8
#define LC 64            // chunk length
#define NCHUNK (SEQ/LC)  // 16
#define LSTR 72          // LDS row stride (bf16): 144B -> 2-way banks on 16-row column reads

typedef __attribute__((ext_vector_type(8))) short bf16x8;
typedef __attribute__((ext_vector_type(4))) float f32x4;

// ---------------- helpers ----------------

__device__ inline float waveReduceSum(float v) {
#pragma unroll
    for (int m = 32; m; m >>= 1) v += __shfl_xor(v, m, 64);
    return v;
}

template <int NWAVES>
__device__ inline float blockReduceSum(float v) {
    __shared__ float tmp[NWAVES];
    int lane = threadIdx.x & 63, wid = threadIdx.x >> 6;
    v = waveReduceSum(v);
    if (lane == 0) tmp[wid] = v;
    __syncthreads();
    float tot = 0.f;
#pragma unroll
    for (int i = 0; i < NWAVES; i++) tot += tmp[i];
    return tot;
}

__device__ inline float sigmoidf_(float x) { return 1.f / (1.f + expf(-x)); }

// float -> bf16 (round-to-nearest-even)
__device__ inline unsigned short f2bf(float f) {
    union { float f; unsigned int u; } v; v.f = f;
    unsigned int r = (v.u + 0x7fffu + ((v.u >> 16) & 1u)) >> 16;
    return (unsigned short)r;
}
__device__ inline float bf2f(unsigned short u) {
    union { unsigned int i; float f; } v; v.i = ((unsigned int)u) << 16; return v.f;
}

__device__ inline void load_lds16(const void* g, void* l) {
    __builtin_amdgcn_global_load_lds((const __attribute__((address_space(1))) void*)g,
                                     (__attribute__((address_space(3))) void*)l, 16, 0, 0);
}

// ---------------- weight build (f32 base + LoRA -> bf16) ----------------

__global__ void build_w_in_kernel(const float* __restrict__ base,
                                  const float* __restrict__ lA,
                                  const float* __restrict__ lB,
                                  unsigned short* __restrict__ W) {  // [NPAD][D_MODEL]
    int idx = blockIdx.x * blockDim.x + threadIdx.x;
    if (idx >= NPAD * D_MODEL) return;
    int r = idx / D_MODEL, c = idx - r * D_MODEL;
    if (r >= D_IN_PROJ) { W[idx] = 0; return; }
    float s = 0.f;
#pragma unroll
    for (int k = 0; k < RANK; k++) s += lB[r * RANK + k] * lA[k * D_MODEL + c];
    W[idx] = f2bf(base[(size_t)r * D_MODEL + c] + SCALE_LORA * s);
}

__global__ void build_w_out_kernel(const float* __restrict__ base,
                                   const float* __restrict__ lA,
                                   const float* __restrict__ lB,
                                   unsigned short* __restrict__ W) { // [D_MODEL][D_INNER]
    int idx = blockIdx.x * blockDim.x + threadIdx.x;
    if (idx >= D_MODEL * D_INNER) return;
    int r = idx / D_INNER, c = idx - r * D_INNER;
    float s = 0.f;
#pragma unroll
    for (int k = 0; k < RANK; k++) s += lB[r * RANK + k] * lA[k * D_INNER + c];
    W[idx] = f2bf(base[idx] + SCALE_LORA * s);
}

// ---------------- rmsnorm + rope -> bf16 ----------------
__global__ __launch_bounds__(384) void rmsrope_kernel(
    const float* __restrict__ x, const float* __restrict__ w,
    unsigned short* __restrict__ out, int loop_i) {
    int row = blockIdx.x;
    const float* xr = x + (size_t)row * D_MODEL;
    int j = threadIdx.x;
    float x0 = xr[2 * j], x1 = xr[2 * j + 1];
    float ss = blockReduceSum<6>(x0 * x0 + x1 * x1);
    float sc = rsqrtf(ss * (1.f / D_MODEL) + 1e-6f);
    float y0 = x0 * sc * w[2 * j];
    float y1 = x1 * sc * w[2 * j + 1];
    float ang = (float)loop_i * expf((float)(2 * j) * (-9.210340371976184f / (float)D_MODEL));
    float c = cosf(ang), sn = sinf(ang);
    unsigned short* orow = out + (size_t)row * D_MODEL;
    orow[2 * j]     = f2bf(y0 * c - y1 * sn);
    orow[2 * j + 1] = f2bf(y1 * c + y0 * sn);
}

// ---------------- bf16 MFMA GEMM, templated tile, 2-phase dbuf + swizzled LDS ----------------
// MODE 2: bf16 store + f32 dt side-channel (GEMM1)
// MODE 3: f32 store with +gate*xp epilogue (GEMM2)
// Wave grid 2x2; wave tile (BMT/2)x(BNT/2); fragment reps FM=BMT/32, FN=BNT/32.
template <int BMT, int BNT, int MODE>
__global__ __launch_bounds__(256) void gemm_tile_kernel(
    const unsigned short* __restrict__ A,
    const unsigned short* __restrict__ B,
    void* __restrict__ Cv, int M, int N, int K, int Cstride,
    float* __restrict__ dtraw,
    const float* __restrict__ xp, const float* __restrict__ gate) {
    constexpr int FM = BMT / 32, FN = BNT / 32;
    __shared__ unsigned short lsA[2][BMT * 64];
    __shared__ unsigned short lsB[2][BNT * 64];
    int t = threadIdx.x;
    int w = t >> 6, lane = t & 63;
    int n0 = blockIdx.x * BNT, m0 = blockIdx.y * BMT;
    int wr = w >> 1, wc = w & 1;
    f32x4 acc[FM][FN];
#pragma unroll
    for (int i = 0; i < FM; i++)
#pragma unroll
        for (int j = 0; j < FN; j++) acc[i][j] = (f32x4){0.f, 0.f, 0.f, 0.f};

#define STAGE(bi, kk0)                                                            \
    {                                                                             \
        _Pragma("unroll")                                                         \
        for (int o = 0; o < BMT / 32; o++) {                                      \
            int s = o * 256 + t;                                                  \
            int row = s >> 3, u = s & 7;                                          \
            int usrc = (u ^ (row & 7)) << 3;                                      \
            load_lds16(&A[(size_t)(m0 + row) * K + (kk0) + usrc],                 \
                       &lsA[bi][(size_t)(o * 256 + (t & ~63)) * 8]);              \
        }                                                                         \
        _Pragma("unroll")                                                         \
        for (int o = 0; o < BNT / 32; o++) {                                      \
            int s = o * 256 + t;                                                  \
            int row = s >> 3, u = s & 7;                                          \
            int usrc = (u ^ (row & 7)) << 3;                                      \
            load_lds16(&B[(size_t)(n0 + row) * K + (kk0) + usrc],                 \
                       &lsB[bi][(size_t)(o * 256 + (t & ~63)) * 8]);              \
        }                                                                         \
    }

    int nk = K >> 6;
    STAGE(0, 0);
    __syncthreads();           // drains vmcnt(0): buffer 0 ready
    int cur = 0;
    for (int ks = 0; ks < nk; ks++) {
        if (ks + 1 < nk) STAGE(cur ^ 1, (ks + 1) * 64);   // prefetch next
#pragma unroll
        for (int kk = 0; kk < 2; kk++) {
            bf16x8 af[FM], bfr[FN];
            int u_t = kk * 4 + (lane >> 4);
            int kof = (u_t ^ (lane & 7)) << 3;    // swizzled read column
#pragma unroll
            for (int i = 0; i < FM; i++) {
                int row = wr * (BMT / 2) + i * 16 + (lane & 15);
                af[i] = *(const bf16x8*)&lsA[cur][row * 64 + kof];
            }
#pragma unroll
            for (int j = 0; j < FN; j++) {
                int row = wc * (BNT / 2) + j * 16 + (lane & 15);
                bfr[j] = *(const bf16x8*)&lsB[cur][row * 64 + kof];
            }
#pragma unroll
            for (int i = 0; i < FM; i++)
#pragma unroll
                for (int j = 0; j < FN; j++)
                    acc[i][j] = __builtin_amdgcn_mfma_f32_16x16x32_bf16(af[i], bfr[j], acc[i][j], 0, 0, 0);
        }
        __syncthreads();       // all waves done with cur; prefetch (vmcnt 0) landed
        cur ^= 1;
    }
#undef STAGE

#pragma unroll
    for (int i = 0; i < FM; i++) {
#pragma unroll
        for (int j = 0; j < FN; j++) {
#pragma unroll
            for (int r = 0; r < 4; r++) {
                int row = m0 + wr * (BMT / 2) + i * 16 + (lane >> 4) * 4 + r;
                int col = n0 + wc * (BNT / 2) + j * 16 + (lane & 15);
                float v = acc[i][j][r];
                if (MODE == 2) {
                    ((unsigned short*)Cv)[(size_t)row * Cstride + col] = f2bf(v);
                    if (col >= 3200 && col < 3224) dtraw[row * 24 + (col - 3200)] = v;
                } else {
                    ((float*)Cv)[(size_t)row * Cstride + col] =
                        v + gate[col] * xp[(size_t)row * Cstride + col];
                }
            }
        }
    }
}

// ---------------- depthwise causal conv + silu (B/C channels only) ----------------
// xbc layout: [NROWS][128]  (0..63 = B, 64..127 = C)
__global__ void conv_bc_kernel(const unsigned short* __restrict__ zxb,
                               const float* __restrict__ cw,
                               const float* __restrict__ cb, float* __restrict__ xbc) {
    int idx = blockIdx.x * blockDim.x + threadIdx.x;   // NROWS*128
    if (idx >= NROWS * 128) return;
    int cbc = idx & 127;
    int row = idx >> 7;
    int l = row & (SEQ - 1);
    int ch = 1536 + cbc;                               // conv channel
    const unsigned short* base = zxb + (size_t)row * ZSTR + 3072 + cbc;
    float acc = cb[ch];
#pragma unroll
    for (int t = 0; t < 4; t++) {
        int ll = l - 3 + t;
        if (ll >= 0) acc = fmaf(cw[ch * 4 + t], bf2f(base[(size_t)(ll - l) * ZSTR]), acc);
    }
    xbc[idx] = acc * sigmoidf_(acc);
}

// ---------------- MFMA chunked scan (X-conv fused) ----------------
__global__ __launch_bounds__(256) void scan_mfma_kernel(
    const unsigned short* __restrict__ zxb,  // [NROWS][ZSTR] bf16
    const float* __restrict__ xbc,           // [NROWS][128]  (B|C)
    const float* __restrict__ dtraw,         // [NROWS][24] f32
    const float* __restrict__ cw, const float* __restrict__ cb,
    const float* __restrict__ dt_bias,
    const float* __restrict__ A_log,
    const float* __restrict__ Dp,
    float* __restrict__ y,           // [NROWS][D_INNER]
    float* __restrict__ Fbuf,        // [blk][n][p]
    float* __restrict__ cumA) {      // [blk][LC]
    __shared__ unsigned short Cc[64][LSTR];
    __shared__ unsigned short Bb[64][LSTR];
    __shared__ unsigned short Xt[64][LSTR];   // Xt[p][u]
    __shared__ unsigned short Bw[64][LSTR];   // Bw[n][u]
    __shared__ unsigned short Mm[64][LSTR];
    __shared__ float s_lds[64];
    __shared__ float dt_lds[64];

    int blk = blockIdx.x;
    int c = blk % NCHUNK;
    int bh = blk / NCHUNK;
    int h = bh % NHEADS, b = bh / NHEADS;
    int tid = threadIdx.x;
    int w = tid >> 6, lane = tid & 63;
    const int t0 = c * LC;

    if (w == 0) {
        int t = lane;
        size_t row = (size_t)(b * SEQ + t0 + t);
        float raw = dtraw[row * 24 + h] + dt_bias[h];
        float dt_t = raw > 20.f ? raw : log1pf(expf(raw));
        float s = dt_t * (-expf(A_log[h]));
#pragma unroll
        for (int off = 1; off < 64; off <<= 1) {
            float v = __shfl_up(s, off, 64);
            if (lane >= off) s += v;
        }
        s_lds[t] = s;
        dt_lds[t] = dt_t;
        cumA[(size_t)blk * LC + t] = expf(s);
    }

    float breg[16];
#pragma unroll
    for (int k = 0; k < 16; k++) {
        int idx = k * 256 + tid;
        int r = idx >> 6, ci = idx & 63;
        int l = t0 + r;
        size_t grow = (size_t)(b * SEQ + l);
        // fused X depthwise conv + silu
        int ch = h * 64 + ci;
        float accv = cb[ch];
        const unsigned short* xin = zxb + grow * ZSTR + 1536 + ch;
#pragma unroll
        for (int tap = 0; tap < 4; tap++) {
            int ll = l - 3 + tap;
            if (ll >= 0) accv = fmaf(cw[ch * 4 + tap], bf2f(xin[(size_t)(tap - 3) * ZSTR]), accv);
        }
        float xv = accv * sigmoidf_(accv);
        Xt[ci][r] = f2bf(xv);
        // B, C from small xbc
        float bv = xbc[grow * 128 + ci];
        float cv = xbc[grow * 128 + 64 + ci];
        Cc[r][ci] = f2bf(cv);
        Bb[r][ci] = f2bf(bv);
        breg[k] = bv;
    }
    __syncthreads();

    float s63 = s_lds[63];
#pragma unroll
    for (int k = 0; k < 16; k++) {
        int idx = k * 256 + tid;
        int r = idx >> 6, ci = idx & 63;
        float wu = expf(s63 - s_lds[r]) * dt_lds[r];
        Bw[ci][r] = f2bf(breg[k] * wu);
    }

    f32x4 accG[4];
#pragma unroll
    for (int j = 0; j < 4; j++) accG[j] = (f32x4){0.f, 0.f, 0.f, 0.f};
#pragma unroll
    for (int kk = 0; kk < 2; kk++) {
        int kof = kk * 32 + (lane >> 4) * 8;
        bf16x8 afr = *(const bf16x8*)&Cc[16 * w + (lane & 15)][kof];
#pragma unroll
        for (int j = 0; j < 4; j++) {
            bf16x8 bfr = *(const bf16x8*)&Bb[16 * j + (lane & 15)][kof];
            accG[j] = __builtin_amdgcn_mfma_f32_16x16x32_bf16(afr, bfr, accG[j], 0, 0, 0);
        }
    }
#pragma unroll
    for (int j = 0; j < 4; j++) {
#pragma unroll
        for (int r = 0; r < 4; r++) {
            int t = 16 * w + (lane >> 4) * 4 + r;
            int u = 16 * j + (lane & 15);
            float v = 0.f;
            if (u <= t) v = accG[j][r] * dt_lds[u] * expf(s_lds[t] - s_lds[u]);
            Mm[t][u] = f2bf(v);
        }
    }
    __syncthreads();

    f32x4 accY[4];
#pragma unroll
    for (int j = 0; j < 4; j++) accY[j] = (f32x4){0.f, 0.f, 0.f, 0.f};
#pragma unroll
    for (int kk = 0; kk < 2; kk++) {
        int kof = kk * 32 + (lane >> 4) * 8;
        bf16x8 afr = *(const bf16x8*)&Mm[16 * w + (lane & 15)][kof];
#pragma unroll
        for (int j = 0; j < 4; j++) {
            bf16x8 bfr = *(const bf16x8*)&Xt[16 * j + (lane & 15)][kof];
            accY[j] = __builtin_amdgcn_mfma_f32_16x16x32_bf16(afr, bfr, accY[j], 0, 0, 0);
        }
    }
    float D_h = Dp[h];
#pragma unroll
    for (int j = 0; j < 4; j++) {
#pragma unroll
        for (int r = 0; r < 4; r++) {
            int t = 16 * w + (lane >> 4) * 4 + r;
            int p = 16 * j + (lane & 15);
            size_t row = (size_t)(b * SEQ + t0 + t);
            float xv = bf2f(Xt[p][t]);
            y[row * D_INNER + h * HEADDIM + p] = accY[j][r] + D_h * xv;
        }
    }

    f32x4 accF[4];
#pragma unroll
    for (int j = 0; j < 4; j++) accF[j] = (f32x4){0.f, 0.f, 0.f, 0.f};
#pragma unroll
    for (int kk = 0; kk < 2; kk++) {
        int kof = kk * 32 + (lane >> 4) * 8;
        bf16x8 afr = *(const bf16x8*)&Bw[16 * w + (lane & 15)][kof];
#pragma unroll
        for (int j = 0; j < 4; j++) {
            bf16x8 bfr = *(const bf16x8*)&Xt[16 * j + (lane & 15)][kof];
            accF[j] = __builtin_amdgcn_mfma_f32_16x16x32_bf16(afr, bfr, accF[j], 0, 0, 0);
        }
    }
#pragma unroll
    for (int j = 0; j < 4; j++) {
#pragma unroll
        for (int r = 0; r < 4; r++) {
            int n = 16 * w + (lane >> 4) * 4 + r;
            int p = 16 * j + (lane & 15);
            Fbuf[(size_t)blk * (HEADDIM * D_STATE) + n * HEADDIM + p] = accF[j][r];
        }
    }
}

// ---------------- ycorr (combine fused): y += cumA[t] * C_t . Hinit ----------------
// Hinit recomputed per block by chaining previous chunks' F (L2-resident).
__global__ __launch_bounds__(256) void ycorr_kernel(
    const float* __restrict__ xbc, const float* __restrict__ cumA,
    const float* __restrict__ Fbuf, float* __restrict__ y) {
    int blk = blockIdx.x;
    int c = blk % NCHUNK;
    if (c == 0) return;                    // Hinit = 0, no correction
    int bh = blk / NCHUNK;
    int h = bh % NHEADS, b = bh / NHEADS;
    int tid = threadIdx.x;

    // chain Hinit over chunks 0..c-1 (layout idx = n*64+p, thread owns idx = tid + k*256)
    float H[16];
#pragma unroll
    for (int k = 0; k < 16; k++) H[k] = 0.f;
    for (int cp = 0; cp < c; cp++) {
        float pA = cumA[(size_t)(bh * NCHUNK + cp) * LC + (LC - 1)];
        size_t base = (size_t)(bh * NCHUNK + cp) * (HEADDIM * D_STATE);
#pragma unroll
        for (int k = 0; k < 16; k++) {
            size_t idx = base + tid + k * 256;
            H[k] = fmaf(pA, H[k], Fbuf[idx]);
        }
    }

    __shared__ float Cd[LC][D_STATE + 1];
    __shared__ float Hs[D_STATE][HEADDIM + 1];
    size_t cbase = (size_t)blk * LC;
#pragma unroll
    for (int k = 0; k < 16; k++) {
        int idx = tid + k * 256;
        int r = idx >> 6, n = idx & 63;
        size_t row = (size_t)(b * SEQ + c * LC + r);
        Cd[r][n] = xbc[row * 128 + 64 + n] * cumA[cbase + r];
        Hs[idx >> 6][idx & 63] = H[k];
    }
    __syncthreads();
    int tx = tid & 15, ty = tid >> 4;
    float acc[4][4] = {};
    for (int n = 0; n < D_STATE; n++) {
        float cv[4], hv[4];
#pragma unroll
        for (int i = 0; i < 4; i++) cv[i] = Cd[ty * 4 + i][n];
#pragma unroll
        for (int j = 0; j < 4; j++) hv[j] = Hs[n][tx * 4 + j];
#pragma unroll
        for (int i = 0; i < 4; i++)
#pragma unroll
            for (int j = 0; j < 4; j++)
                acc[i][j] = fmaf(cv[i], hv[j], acc[i][j]);
    }
#pragma unroll
    for (int i = 0; i < 4; i++) {
        int tt = ty * 4 + i;
        size_t row = (size_t)(b * SEQ + c * LC + tt);
#pragma unroll
        for (int j = 0; j < 4; j++) {
            int p = tx * 4 + j;
            size_t oidx = row * D_INNER + h * HEADDIM + p;
            y[oidx] += acc[i][j];
        }
    }
}

// ---------------- gated rmsnorm -> bf16 ----------------
__global__ __launch_bounds__(256) void gatenorm_kernel(
    const float* __restrict__ y, const unsigned short* __restrict__ zxb,
    const float* __restrict__ w, unsigned short* __restrict__ out) {
    int row = blockIdx.x;
    const unsigned short* z = zxb + (size_t)row * ZSTR;
    const float* yr = y + (size_t)row * D_INNER;
    float g[6];
    float ss = 0.f;
#pragma unroll
    for (int e = 0; e < 6; e++) {
        int idx = threadIdx.x + e * 256;
        float zv = bf2f(z[idx]);
        float gv = yr[idx] * (zv * sigmoidf_(zv));
        g[e] = gv;
        ss += gv * gv;
    }
    ss = blockReduceSum<4>(ss);
    float sc = rsqrtf(ss * (1.f / D_INNER) + 1e-6f);
#pragma unroll
    for (int e = 0; e < 6; e++) {
        int idx = threadIdx.x + e * 256;
        out[(size_t)row * D_INNER + idx] = f2bf(g[e] * sc * w[idx]);
    }
}

// ---------------- launch ----------------
extern "C" void kernel_launch(void* const* d_in, const int* in_sizes, int n_in,
                              void* d_out, int out_size, void* d_ws, size_t ws_size,
                              hipStream_t stream) {
    const float* x        = (const float*)d_in[0];
    const float* x_prompt = (const float*)d_in[1];
    const float* in_base  = (const float*)d_in[2];
    const float* lA_in    = (const float*)d_in[3];
    const float* lB_in    = (const float*)d_in[4];
    const float* conv_w   = (const float*)d_in[5];
    const float* conv_b   = (const float*)d_in[6];
    const float* dt_bias  = (const float*)d_in[7];
    const float* A_log    = (const float*)d_in[8];
    const float* D_param  = (const float*)d_in[9];
    const float* gnw      = (const float*)d_in[10];
    const float* out_base = (const float*)d_in[11];
    const float* lA_out   = (const float*)d_in[12];
    const float* lB_out   = (const float*)d_in[13];
    const float* loop_nw  = (const float*)d_in[14];
    const float* gate     = (const float*)d_in[15];
    float* out = (float*)d_out;

    float* ws_f = (float*)d_ws;
    float* dtraw = ws_f;                                   // 2048*24 f32
    float* xbc   = dtraw + (size_t)NROWS * 24;             // 2048*128 f32
    float* ybuf  = xbc   + (size_t)NROWS * 128;            // 2048*1536 f32
    float* Fbuf  = ybuf  + (size_t)NROWS * D_INNER;        // 768*4096 f32
    float* cumA  = Fbuf  + (size_t)BSZ * NHEADS * NCHUNK * HEADDIM * D_STATE; // 768*64
    unsigned short* zxb   = (unsigned short*)(cumA + (size_t)BSZ * NHEADS * NCHUNK * LC); // 2048*3328 bf16
    unsigned short* W_in  = zxb   + (size_t)NROWS * ZSTR;
    unsigned short* W_out = W_in  + (size_t)NPAD * D_MODEL;
    unsigned short* hbuf  = W_out + (size_t)D_MODEL * D_INNER;
    unsigned short* ygt   = hbuf  + (size_t)NROWS * D_MODEL;

    build_w_in_kernel<<<(NPAD * D_MODEL + 255) / 256, 256, 0, stream>>>(in_base, lA_in, lB_in, W_in);
    build_w_out_kernel<<<(D_MODEL * D_INNER + 255) / 256, 256, 0, stream>>>(out_base, lA_out, lB_out, W_out);

    for (int i = 0; i < 2; i++) {   // n_loops = 2 (fixed by setup_inputs)
        const float* xsrc = (i == 0) ? x : out;
        rmsrope_kernel<<<NROWS, 384, 0, stream>>>(xsrc, loop_nw, hbuf, i);

        // GEMM1: zxb(bf16) = hbuf . W_in^T  (64x128 tile, 832 blocks)
        dim3 g1(NPAD / 128, NROWS / 64);
        gemm_tile_kernel<64, 128, 2><<<g1, 256, 0, stream>>>(
            hbuf, W_in, zxb, NROWS, NPAD, D_MODEL, ZSTR, dtraw, nullptr, nullptr);

        conv_bc_kernel<<<(NROWS * 128 + 255) / 256, 256, 0, stream>>>(zxb, conv_w, conv_b, xbc);

        scan_mfma_kernel<<<BSZ * NHEADS * NCHUNK, 256, 0, stream>>>(
            zxb, xbc, dtraw, conv_w, conv_b, dt_bias, A_log, D_param, ybuf, Fbuf, cumA);
        ycorr_kernel<<<BSZ * NHEADS * NCHUNK, 256, 0, stream>>>(xbc, cumA, Fbuf, ybuf);

        gatenorm_kernel<<<NROWS, 256, 0, stream>>>(ybuf, zxb, gnw, ygt);

        // GEMM2: out = ygt . W_out^T + gate*x_prompt  (64x64 tile, 384 blocks, no atomics)
        dim3 g2(D_MODEL / 64, NROWS / 64);
        gemm_tile_kernel<64, 64, 3><<<g2, 256, 0, stream>>>(
            ygt, W_out, out, NROWS, D_MODEL, D_INNER, D_MODEL, nullptr, x_prompt, gate);
    }
}